// Round 2
// baseline (733.408 us; speedup 1.0000x reference)
//
#include <hip/hip_runtime.h>
#include <hip/hip_bf16.h>

#define BB 8
#define NN 16384
#define SS 1024
#define NSMP 64
#define DD 128
#define R2 0.04f
#define EPSV 1e-5f

typedef short short8 __attribute__((ext_vector_type(8)));
typedef float float4v __attribute__((ext_vector_type(4)));

static __device__ inline unsigned short f2bf(float f) {
  unsigned u = __builtin_bit_cast(unsigned, f);
  unsigned r = (u + 0x7fffu + ((u >> 16) & 1u)) >> 16;
  return (unsigned short)r;
}

// ---- workspace layout (bytes) ----
#define O_PT    0ull                  // ptsT bf16 [B][N][128]: 33,554,432
#define O_Y0    33554432ull           // y0 fp8 [8192][64][128]: 67,108,864
#define O_Y1    100663296ull          // y1 fp8: 67,108,864
#define O_IDX   167772160ull          // idx int32: 2,097,152
#define O_MAXB  169869312ull          // 8,388,608
#define O_MINB  178257920ull          // 8,388,608
#define O_W0B   186646528ull          // bf16 [128][160]: 40,960
#define O_W1B   186687488ull          // bf16 [128][128]: 32,768
#define O_W2B   186720256ull          // bf16 [256][128]: 65,536
#define O_PS0   186785792ull          // 128*256*4
#define O_PQ0   186916864ull
#define O_PS1   187047936ull
#define O_PQ1   187179008ull
#define O_PS2   187310080ull          // 256*256*4
#define O_PQ2   187572224ull
#define O_SC0   187834368ull
#define O_SH0   187834880ull
#define O_SC1   187835392ull
#define O_SH1   187835904ull
#define O_SC2   187836416ull
#define O_SH2   187837440ull
#define WS_NEEDED 187838464ull
#define PART_BYTES 1048576ull

#define OUT_XYZ 0
#define OUT_FEAT 24576
#define OUT_FPS (24576 + 2097152)

// points [B,D,N] fp32 -> ptsT [B,N,D] bf16
__global__ __launch_bounds__(256) void k_transpose_pts(const float* __restrict__ pts,
                                                       short* __restrict__ ptsT) {
  __shared__ float tile[32][33];
  int b = blockIdx.z;
  int n0 = blockIdx.x * 32, c0 = blockIdx.y * 32;
  int tx = threadIdx.x, ty = threadIdx.y;
#pragma unroll
  for (int k = 0; k < 4; k++) {
    int c = c0 + ty + k * 8;
    tile[ty + k * 8][tx] = pts[((size_t)b * DD + c) * NN + n0 + tx];
  }
  __syncthreads();
#pragma unroll
  for (int k = 0; k < 4; k++) {
    int n = n0 + ty + k * 8;
    ptsT[((size_t)b * NN + n) * DD + c0 + tx] = (short)f2bf(tile[tx][ty + k * 8]);
  }
}

// weights -> bf16 rows. W0b[o][kn]: kn 0..127 = feats (orig c=kn+3), 128..130 = xyz, 131..159 = 0.
__global__ __launch_bounds__(256) void k_wt(const float* __restrict__ W0, const float* __restrict__ W1,
                                            const float* __restrict__ W2, short* __restrict__ W0b,
                                            short* __restrict__ W1b, short* __restrict__ W2b) {
  int id = blockIdx.x * 256 + threadIdx.x;
  if (id < 128 * 160) {
    int o = id / 160, kn = id % 160;
    float v = 0.f;
    if (kn < 128) v = W0[o * 131 + kn + 3];
    else if (kn < 131) v = W0[o * 131 + (kn - 128)];
    W0b[id] = (short)f2bf(v);
  } else if (id < 128 * 160 + 128 * 128) {
    int j = id - 128 * 160;
    W1b[j] = (short)f2bf(W1[j]);
  } else if (id < 128 * 160 + 128 * 128 + 256 * 128) {
    int j = id - (128 * 160 + 128 * 128);
    W2b[j] = (short)f2bf(W2[j]);
  }
}

__global__ __launch_bounds__(256) void k_newxyz(const float* __restrict__ xyz, const int* __restrict__ fps,
                                                float* __restrict__ out) {
  int id = blockIdx.x * 256 + threadIdx.x;  // B*S
  int fi = fps[id];
  int b = id >> 10;
  const float* p = xyz + ((size_t)b * NN + fi) * 3;
  float* o = out + OUT_XYZ + (size_t)id * 3;
  o[0] = p[0]; o[1] = p[1]; o[2] = p[2];
  out[OUT_FPS + id] = (float)fi;
}

// one wave per (b,s): first-NS valid indices in ascending n, pad with first valid
// (FP expression order kept bit-identical to R1 — error budget is dominated by these boundaries)
__global__ __launch_bounds__(256) void k_ballq(const float* __restrict__ xyz, const int* __restrict__ fps,
                                               int* __restrict__ idxb) {
  int w = (blockIdx.x * 256 + threadIdx.x) >> 6;
  int lane = threadIdx.x & 63;
  int b = w >> 10;
  int fi = fps[w];
  const float* cp = xyz + ((size_t)b * NN + fi) * 3;
  float cx = cp[0], cy = cp[1], cz = cp[2];
  float A = __fadd_rn(__fadd_rn(__fmul_rn(cx, cx), __fmul_rn(cy, cy)), __fmul_rn(cz, cz));
  const float* xb = xyz + (size_t)b * NN * 3;
  int cnt = 0, firstn = -1;
  int* myidx = idxb + (size_t)w * NSMP;
  for (int nb = 0; nb < NN && cnt < NSMP; nb += 64) {
    int n = nb + lane;
    float px = xb[n * 3], py = xb[n * 3 + 1], pz = xb[n * 3 + 2];
    float Bv = __fadd_rn(__fadd_rn(__fmul_rn(px, px), __fmul_rn(py, py)), __fmul_rn(pz, pz));
    float dot = __fadd_rn(__fadd_rn(__fmul_rn(cx, px), __fmul_rn(cy, py)), __fmul_rn(cz, pz));
    float d = __fsub_rn(__fadd_rn(A, Bv), __fmul_rn(2.0f, dot));
    bool valid = !(d > R2);
    unsigned long long mask = __ballot(valid);
    if (firstn < 0 && mask) firstn = nb + __builtin_ctzll(mask);
    int prefix = __popcll(mask & ((1ull << lane) - 1ull));
    int pos = cnt + prefix;
    if (valid && pos < NSMP) myidx[pos] = n;
    cnt += __popcll(mask);
    if (cnt > NSMP) cnt = NSMP;
  }
  if (lane >= cnt) myidx[lane] = firstn;
}

// layer0: gather bf16 -> MFMA GEMM (K=160 padded) -> stats + y0 fp8
__global__ __launch_bounds__(256, 2) void k_mlp0(const float* __restrict__ xyz,
                                                 const short* __restrict__ ptsT,
                                                 const int* __restrict__ fps, const int* __restrict__ idxb,
                                                 const short* __restrict__ W0b, const float* __restrict__ b0,
                                                 unsigned char* __restrict__ y0, float* __restrict__ psum,
                                                 float* __restrict__ psq) {
  __shared__ short xs[64 * 168];  // [row][160+8 pad]
  __shared__ __align__(16) unsigned char ys8[8192];
  __shared__ int smidx[64];
  __shared__ float smc[3];
  int t = threadIdx.x;
  int bs = blockIdx.x;
  int b = bs >> 10;
  if (t < 64) smidx[t] = idxb[(size_t)bs * 64 + t];
  if (t < 3) {
    int fi = fps[bs];
    smc[t] = xyz[((size_t)b * NN + fi) * 3 + t];
  }
  __syncthreads();
  {
    int row = t >> 2, part = t & 3;
    int n = smidx[row];
    const short8* srcp = (const short8*)(ptsT + ((size_t)b * NN + n) * DD);
#pragma unroll
    for (int i = 0; i < 4; i++) {
      int ch = part * 4 + i;
      *(short8*)&xs[row * 168 + ch * 8] = srcp[ch];
    }
  }
  if (t < 64) {
    int n = smidx[t];
    const float* p = xyz + ((size_t)b * NN + n) * 3;
    xs[t * 168 + 128] = (short)f2bf(p[0] - smc[0]);
    xs[t * 168 + 129] = (short)f2bf(p[1] - smc[1]);
    xs[t * 168 + 130] = (short)f2bf(p[2] - smc[2]);
#pragma unroll
    for (int c2 = 131; c2 < 160; c2++) xs[t * 168 + c2] = 0;
  }
  __syncthreads();
  const int lane = t & 63, w = t >> 6, quad = lane >> 4, l15 = lane & 15;
  float4v acc[2][4];
#pragma unroll
  for (int j = 0; j < 2; j++) {
    float bj = b0[w * 32 + j * 16 + l15];
#pragma unroll
    for (int mi = 0; mi < 4; mi++) acc[j][mi] = (float4v){bj, bj, bj, bj};
  }
#pragma unroll
  for (int ks = 0; ks < 5; ks++) {
    short8 am[4], bw[2];
#pragma unroll
    for (int mi = 0; mi < 4; mi++)
      am[mi] = *(const short8*)&xs[(mi * 16 + l15) * 168 + ks * 32 + quad * 8];
#pragma unroll
    for (int j = 0; j < 2; j++) {
      int o = w * 32 + j * 16 + l15;
      bw[j] = *(const short8*)&W0b[o * 160 + ks * 32 + quad * 8];
    }
#pragma unroll
    for (int j = 0; j < 2; j++)
#pragma unroll
      for (int mi = 0; mi < 4; mi++)
        acc[j][mi] = __builtin_amdgcn_mfma_f32_16x16x32_bf16(am[mi], bw[j], acc[j][mi], 0, 0, 0);
  }
#pragma unroll
  for (int j = 0; j < 2; j++) {
    float s = 0.f, q = 0.f;
#pragma unroll
    for (int mi = 0; mi < 4; mi++)
#pragma unroll
      for (int r = 0; r < 4; r++) { float v = acc[j][mi][r]; s += v; q = fmaf(v, v, q); }
    s += __shfl_down(s, 32); q += __shfl_down(q, 32);
    s += __shfl_down(s, 16); q += __shfl_down(q, 16);
    int col = w * 32 + j * 16 + l15;
    if (lane < 16) {
      int slot = bs & 255;
      atomicAdd(&psum[col * 256 + slot], s);
      atomicAdd(&psq[col * 256 + slot], q);
    }
#pragma unroll
    for (int mi = 0; mi < 4; mi++)
#pragma unroll
      for (int r = 0; r < 4; r++) {
        int rowi = mi * 16 + quad * 4 + r;
        int pk = __builtin_amdgcn_cvt_pk_fp8_f32(acc[j][mi][r], acc[j][mi][r], 0, false);
        ys8[rowi * 128 + col] = (unsigned char)(pk & 0xff);
      }
  }
  __syncthreads();
  {
    const uint4* yst = (const uint4*)ys8;
    uint4* dst = (uint4*)(y0 + (size_t)bs * 8192);
    dst[2 * t] = yst[2 * t];
    dst[2 * t + 1] = yst[2 * t + 1];
  }
}

// layer1: y0 fp8 -> affine+relu -> bf16 xs; MFMA GEMM K=128; stats + y1 fp8
__global__ __launch_bounds__(256, 2) void k_mlp1(const unsigned char* __restrict__ y0,
                                                 const float* __restrict__ sc, const float* __restrict__ sh,
                                                 const short* __restrict__ W1b, const float* __restrict__ b1,
                                                 unsigned char* __restrict__ y1, float* __restrict__ psum,
                                                 float* __restrict__ psq) {
  __shared__ short xs[64 * 136];
  __shared__ __align__(16) unsigned char ys8[8192];
  __shared__ float ssc[128], ssh[128];
  int t = threadIdx.x;
  int bs = blockIdx.x;
  if (t < 128) { ssc[t] = sc[t]; ssh[t] = sh[t]; }
  __syncthreads();
  {
    const uint4* srcp = (const uint4*)(y0 + (size_t)bs * 8192) + 2 * t;
    uint4 d0 = srcp[0], d1 = srcp[1];
    unsigned dw[8] = {d0.x, d0.y, d0.z, d0.w, d1.x, d1.y, d1.z, d1.w};
    int row = t >> 2, cb = (t & 3) * 32;
#pragma unroll
    for (int dd = 0; dd < 8; dd++) {
      int c = cb + dd * 4;
      float f0 = __builtin_amdgcn_cvt_f32_fp8(dw[dd], 0);
      float f1 = __builtin_amdgcn_cvt_f32_fp8(dw[dd], 1);
      float f2 = __builtin_amdgcn_cvt_f32_fp8(dw[dd], 2);
      float f3 = __builtin_amdgcn_cvt_f32_fp8(dw[dd], 3);
      float x0 = fmaxf(fmaf(f0, ssc[c], ssh[c]), 0.f);
      float x1 = fmaxf(fmaf(f1, ssc[c + 1], ssh[c + 1]), 0.f);
      float x2 = fmaxf(fmaf(f2, ssc[c + 2], ssh[c + 2]), 0.f);
      float x3 = fmaxf(fmaf(f3, ssc[c + 3], ssh[c + 3]), 0.f);
      unsigned p0 = (unsigned)f2bf(x0) | ((unsigned)f2bf(x1) << 16);
      unsigned p1 = (unsigned)f2bf(x2) | ((unsigned)f2bf(x3) << 16);
      unsigned* dst = (unsigned*)&xs[row * 136 + c];
      dst[0] = p0; dst[1] = p1;
    }
  }
  __syncthreads();
  const int lane = t & 63, w = t >> 6, quad = lane >> 4, l15 = lane & 15;
  float4v acc[2][4];
#pragma unroll
  for (int j = 0; j < 2; j++) {
    float bj = b1[w * 32 + j * 16 + l15];
#pragma unroll
    for (int mi = 0; mi < 4; mi++) acc[j][mi] = (float4v){bj, bj, bj, bj};
  }
#pragma unroll
  for (int ks = 0; ks < 4; ks++) {
    short8 am[4], bw[2];
#pragma unroll
    for (int mi = 0; mi < 4; mi++)
      am[mi] = *(const short8*)&xs[(mi * 16 + l15) * 136 + ks * 32 + quad * 8];
#pragma unroll
    for (int j = 0; j < 2; j++) {
      int o = w * 32 + j * 16 + l15;
      bw[j] = *(const short8*)&W1b[o * 128 + ks * 32 + quad * 8];
    }
#pragma unroll
    for (int j = 0; j < 2; j++)
#pragma unroll
      for (int mi = 0; mi < 4; mi++)
        acc[j][mi] = __builtin_amdgcn_mfma_f32_16x16x32_bf16(am[mi], bw[j], acc[j][mi], 0, 0, 0);
  }
#pragma unroll
  for (int j = 0; j < 2; j++) {
    float s = 0.f, q = 0.f;
#pragma unroll
    for (int mi = 0; mi < 4; mi++)
#pragma unroll
      for (int r = 0; r < 4; r++) { float v = acc[j][mi][r]; s += v; q = fmaf(v, v, q); }
    s += __shfl_down(s, 32); q += __shfl_down(q, 32);
    s += __shfl_down(s, 16); q += __shfl_down(q, 16);
    int col = w * 32 + j * 16 + l15;
    if (lane < 16) {
      int slot = bs & 255;
      atomicAdd(&psum[col * 256 + slot], s);
      atomicAdd(&psq[col * 256 + slot], q);
    }
#pragma unroll
    for (int mi = 0; mi < 4; mi++)
#pragma unroll
      for (int r = 0; r < 4; r++) {
        int rowi = mi * 16 + quad * 4 + r;
        int pk = __builtin_amdgcn_cvt_pk_fp8_f32(acc[j][mi][r], acc[j][mi][r], 0, false);
        ys8[rowi * 128 + col] = (unsigned char)(pk & 0xff);
      }
  }
  __syncthreads();
  {
    const uint4* yst = (const uint4*)ys8;
    uint4* dst = (uint4*)(y1 + (size_t)bs * 8192);
    dst[2 * t] = yst[2 * t];
    dst[2 * t + 1] = yst[2 * t + 1];
  }
}

// layer2: y1 fp8 -> affine+relu -> bf16 xs; MFMA GEMM Nout=256; stats + per-(bs,o) max/min
__global__ __launch_bounds__(256, 2) void k_mlp2(const unsigned char* __restrict__ y1,
                                                 const float* __restrict__ sc, const float* __restrict__ sh,
                                                 const short* __restrict__ W2b, const float* __restrict__ b2,
                                                 float* __restrict__ maxb, float* __restrict__ minb,
                                                 float* __restrict__ psum, float* __restrict__ psq) {
  __shared__ short xs[64 * 136];
  __shared__ float ssc[128], ssh[128];
  int t = threadIdx.x;
  int bs = blockIdx.x;
  if (t < 128) { ssc[t] = sc[t]; ssh[t] = sh[t]; }
  __syncthreads();
  {
    const uint4* srcp = (const uint4*)(y1 + (size_t)bs * 8192) + 2 * t;
    uint4 d0 = srcp[0], d1 = srcp[1];
    unsigned dw[8] = {d0.x, d0.y, d0.z, d0.w, d1.x, d1.y, d1.z, d1.w};
    int row = t >> 2, cb = (t & 3) * 32;
#pragma unroll
    for (int dd = 0; dd < 8; dd++) {
      int c = cb + dd * 4;
      float f0 = __builtin_amdgcn_cvt_f32_fp8(dw[dd], 0);
      float f1 = __builtin_amdgcn_cvt_f32_fp8(dw[dd], 1);
      float f2 = __builtin_amdgcn_cvt_f32_fp8(dw[dd], 2);
      float f3 = __builtin_amdgcn_cvt_f32_fp8(dw[dd], 3);
      float x0 = fmaxf(fmaf(f0, ssc[c], ssh[c]), 0.f);
      float x1 = fmaxf(fmaf(f1, ssc[c + 1], ssh[c + 1]), 0.f);
      float x2 = fmaxf(fmaf(f2, ssc[c + 2], ssh[c + 2]), 0.f);
      float x3 = fmaxf(fmaf(f3, ssc[c + 3], ssh[c + 3]), 0.f);
      unsigned p0 = (unsigned)f2bf(x0) | ((unsigned)f2bf(x1) << 16);
      unsigned p1 = (unsigned)f2bf(x2) | ((unsigned)f2bf(x3) << 16);
      unsigned* dst = (unsigned*)&xs[row * 136 + c];
      dst[0] = p0; dst[1] = p1;
    }
  }
  __syncthreads();
  const int lane = t & 63, w = t >> 6, quad = lane >> 4, l15 = lane & 15;
  float4v acc[4][4];
#pragma unroll
  for (int j = 0; j < 4; j++) {
    float bj = b2[w * 64 + j * 16 + l15];
#pragma unroll
    for (int mi = 0; mi < 4; mi++) acc[j][mi] = (float4v){bj, bj, bj, bj};
  }
#pragma unroll
  for (int ks = 0; ks < 4; ks++) {
    short8 am[4], bw[4];
#pragma unroll
    for (int mi = 0; mi < 4; mi++)
      am[mi] = *(const short8*)&xs[(mi * 16 + l15) * 136 + ks * 32 + quad * 8];
#pragma unroll
    for (int j = 0; j < 4; j++) {
      int o = w * 64 + j * 16 + l15;
      bw[j] = *(const short8*)&W2b[o * 128 + ks * 32 + quad * 8];
    }
#pragma unroll
    for (int j = 0; j < 4; j++)
#pragma unroll
      for (int mi = 0; mi < 4; mi++)
        acc[j][mi] = __builtin_amdgcn_mfma_f32_16x16x32_bf16(am[mi], bw[j], acc[j][mi], 0, 0, 0);
  }
#pragma unroll
  for (int j = 0; j < 4; j++) {
    float s = 0.f, q = 0.f, mx = -3.4e38f, mn = 3.4e38f;
#pragma unroll
    for (int mi = 0; mi < 4; mi++)
#pragma unroll
      for (int r = 0; r < 4; r++) {
        float v = acc[j][mi][r];
        s += v; q = fmaf(v, v, q);
        mx = fmaxf(mx, v); mn = fminf(mn, v);
      }
    s += __shfl_down(s, 32); q += __shfl_down(q, 32);
    mx = fmaxf(mx, __shfl_down(mx, 32)); mn = fminf(mn, __shfl_down(mn, 32));
    s += __shfl_down(s, 16); q += __shfl_down(q, 16);
    mx = fmaxf(mx, __shfl_down(mx, 16)); mn = fminf(mn, __shfl_down(mn, 16));
    int col = w * 64 + j * 16 + l15;
    if (lane < 16) {
      int slot = bs & 255;
      atomicAdd(&psum[col * 256 + slot], s);
      atomicAdd(&psq[col * 256 + slot], q);
      maxb[(size_t)bs * 256 + col] = mx;
      minb[(size_t)bs * 256 + col] = mn;
    }
  }
}

// fold BN stats into per-channel affine: a = g*rsqrt(var+eps); c = be - mean*a
__global__ __launch_bounds__(256) void k_fin(const float* __restrict__ psum, const float* __restrict__ psq,
                                             const float* __restrict__ g, const float* __restrict__ be,
                                             float* __restrict__ sc, float* __restrict__ sh, int nch) {
  int o = threadIdx.x;
  if (o >= nch) return;
  float s = 0.f, q = 0.f;
  for (int k = 0; k < 256; k++) {
    s += psum[o * 256 + k];
    q += psq[o * 256 + k];
  }
  const float inv = 1.0f / 524288.0f;
  float m = s * inv;
  float ey2 = q * inv;
  float v = fmaf(-m, m, ey2);
  v = fmaxf(v, 0.f);
  float r = rsqrtf(v + EPSV);
  float a = g[o] * r;
  sc[o] = a;
  sh[o] = fmaf(-m, a, be[o]);
}

// out[b, o, s] = relu(a*sel + c), sel = max if a>=0 else min
__global__ __launch_bounds__(256) void k_out(const float* __restrict__ maxb, const float* __restrict__ minb,
                                             const float* __restrict__ sc, const float* __restrict__ sh,
                                             float* __restrict__ out) {
  int flat = blockIdx.x * 256 + threadIdx.x;  // 2,097,152
  int b = flat >> 18;
  int o = (flat >> 10) & 255;
  int s = flat & 1023;
  float a = sc[o], c_ = sh[o];
  size_t mi = ((size_t)(b * 1024 + s)) * 256 + o;
  float v = (a >= 0.f) ? maxb[mi] : minb[mi];
  out[OUT_FEAT + flat] = fmaxf(fmaf(a, v, c_), 0.f);
}

extern "C" void kernel_launch(void* const* d_in, const int* in_sizes, int n_in,
                              void* d_out, int out_size, void* d_ws, size_t ws_size,
                              hipStream_t stream) {
  const float* xyz = (const float*)d_in[0];
  const float* pts = (const float*)d_in[1];
  const int* fps = (const int*)d_in[2];
  const float* W0 = (const float*)d_in[3];
  const float* b0 = (const float*)d_in[4];
  const float* g0 = (const float*)d_in[5];
  const float* be0 = (const float*)d_in[6];
  const float* W1 = (const float*)d_in[7];
  const float* b1 = (const float*)d_in[8];
  const float* g1 = (const float*)d_in[9];
  const float* be1 = (const float*)d_in[10];
  const float* W2 = (const float*)d_in[11];
  const float* b2 = (const float*)d_in[12];
  const float* g2 = (const float*)d_in[13];
  const float* be2 = (const float*)d_in[14];
  float* out = (float*)d_out;
  char* ws = (char*)d_ws;

  k_newxyz<<<32, 256, 0, stream>>>(xyz, fps, out);
  if (ws_size < WS_NEEDED) return;

  short* ptsT = (short*)(ws + O_PT);
  unsigned char* y0 = (unsigned char*)(ws + O_Y0);
  unsigned char* y1 = (unsigned char*)(ws + O_Y1);
  int* idxb = (int*)(ws + O_IDX);
  float* maxbf = (float*)(ws + O_MAXB);
  float* minbf = (float*)(ws + O_MINB);
  short* W0b = (short*)(ws + O_W0B);
  short* W1b = (short*)(ws + O_W1B);
  short* W2b = (short*)(ws + O_W2B);
  float* ps0 = (float*)(ws + O_PS0);
  float* pq0 = (float*)(ws + O_PQ0);
  float* ps1 = (float*)(ws + O_PS1);
  float* pq1 = (float*)(ws + O_PQ1);
  float* ps2 = (float*)(ws + O_PS2);
  float* pq2 = (float*)(ws + O_PQ2);
  float* sc0 = (float*)(ws + O_SC0);
  float* sh0 = (float*)(ws + O_SH0);
  float* sc1 = (float*)(ws + O_SC1);
  float* sh1 = (float*)(ws + O_SH1);
  float* sc2 = (float*)(ws + O_SC2);
  float* sh2 = (float*)(ws + O_SH2);

  hipMemsetAsync(ws + O_PS0, 0, PART_BYTES, stream);
  k_transpose_pts<<<dim3(NN / 32, DD / 32, BB), dim3(32, 8), 0, stream>>>(pts, ptsT);
  k_wt<<<272, 256, 0, stream>>>(W0, W1, W2, W0b, W1b, W2b);
  k_ballq<<<2048, 256, 0, stream>>>(xyz, fps, idxb);
  k_mlp0<<<8192, 256, 0, stream>>>(xyz, ptsT, fps, idxb, W0b, b0, y0, ps0, pq0);
  k_fin<<<1, 256, 0, stream>>>(ps0, pq0, g0, be0, sc0, sh0, 128);
  k_mlp1<<<8192, 256, 0, stream>>>(y0, sc0, sh0, W1b, b1, y1, ps1, pq1);
  k_fin<<<1, 256, 0, stream>>>(ps1, pq1, g1, be1, sc1, sh1, 128);
  k_mlp2<<<8192, 256, 0, stream>>>(y1, sc1, sh1, W2b, b2, maxbf, minbf, ps2, pq2);
  k_fin<<<1, 256, 0, stream>>>(ps2, pq2, g2, be2, sc2, sh2, 256);
  k_out<<<8192, 256, 0, stream>>>(maxbf, minbf, sc2, sh2, out);
}

// Round 3
// 435.231 us; speedup vs baseline: 1.6851x; 1.6851x over previous
//
#include <hip/hip_runtime.h>
#include <hip/hip_bf16.h>

#define BB 8
#define NN 16384
#define SS 1024
#define NSMP 64
#define DD 128
#define R2 0.04f
#define EPSV 1e-5f
#define G 8          // groups (b,s) per mlp block
#define NBLK 1024    // mlp grid

typedef short short8 __attribute__((ext_vector_type(8)));
typedef float float4v __attribute__((ext_vector_type(4)));

static __device__ inline unsigned short f2bf(float f) {
  unsigned u = __builtin_bit_cast(unsigned, f);
  unsigned r = (u + 0x7fffu + ((u >> 16) & 1u)) >> 16;
  return (unsigned short)r;
}

// ---- workspace layout (bytes) ----
#define O_PT    0ull                  // ptsT bf16 [B][N][128]: 33,554,432
#define O_Y0    33554432ull           // y0 fp8: 67,108,864
#define O_Y1    100663296ull          // y1 fp8: 67,108,864
#define O_IDX   167772160ull          // idx int32: 2,097,152
#define O_MAXB  169869312ull          // 8,388,608
#define O_MINB  178257920ull          // 8,388,608
#define O_W0B   186646528ull          // bf16 [128][160]: 40,960
#define O_W1B   186687488ull          // bf16 [128][128]: 32,768
#define O_W2B   186720256ull          // bf16 [256][128]: 65,536
#define O_P0S   186785792ull          // [1024][128] f32: 524,288
#define O_P0Q   187310080ull
#define O_P1S   187834368ull
#define O_P1Q   188358656ull
#define O_P2S   188882944ull          // [1024][256] f32: 1,048,576
#define O_P2Q   189931520ull
#define O_SC0   190980096ull
#define O_SH0   190980608ull
#define O_SC1   190981120ull
#define O_SH1   190981632ull
#define O_SC2   190982144ull          // 1024
#define O_SH2   190983168ull
#define WS_NEEDED 190984192ull

#define OUT_XYZ 0
#define OUT_FEAT 24576
#define OUT_FPS (24576 + 2097152)

// points [B,D,N] fp32 -> ptsT [B,N,D] bf16
__global__ __launch_bounds__(256) void k_transpose_pts(const float* __restrict__ pts,
                                                       short* __restrict__ ptsT) {
  __shared__ float tile[32][33];
  int b = blockIdx.z;
  int n0 = blockIdx.x * 32, c0 = blockIdx.y * 32;
  int tx = threadIdx.x, ty = threadIdx.y;
#pragma unroll
  for (int k = 0; k < 4; k++) {
    int c = c0 + ty + k * 8;
    tile[ty + k * 8][tx] = pts[((size_t)b * DD + c) * NN + n0 + tx];
  }
  __syncthreads();
#pragma unroll
  for (int k = 0; k < 4; k++) {
    int n = n0 + ty + k * 8;
    ptsT[((size_t)b * NN + n) * DD + c0 + tx] = (short)f2bf(tile[tx][ty + k * 8]);
  }
}

// weights -> bf16 rows. W0b[o][kn]: kn 0..127 = feats (orig c=kn+3), 128..130 = xyz, 131..159 = 0.
__global__ __launch_bounds__(256) void k_wt(const float* __restrict__ W0, const float* __restrict__ W1,
                                            const float* __restrict__ W2, short* __restrict__ W0b,
                                            short* __restrict__ W1b, short* __restrict__ W2b) {
  int id = blockIdx.x * 256 + threadIdx.x;
  if (id < 128 * 160) {
    int o = id / 160, kn = id % 160;
    float v = 0.f;
    if (kn < 128) v = W0[o * 131 + kn + 3];
    else if (kn < 131) v = W0[o * 131 + (kn - 128)];
    W0b[id] = (short)f2bf(v);
  } else if (id < 128 * 160 + 128 * 128) {
    int j = id - 128 * 160;
    W1b[j] = (short)f2bf(W1[j]);
  } else if (id < 128 * 160 + 128 * 128 + 256 * 128) {
    int j = id - (128 * 160 + 128 * 128);
    W2b[j] = (short)f2bf(W2[j]);
  }
}

__global__ __launch_bounds__(256) void k_newxyz(const float* __restrict__ xyz, const int* __restrict__ fps,
                                                float* __restrict__ out) {
  int id = blockIdx.x * 256 + threadIdx.x;  // B*S
  int fi = fps[id];
  int b = id >> 10;
  const float* p = xyz + ((size_t)b * NN + fi) * 3;
  float* o = out + OUT_XYZ + (size_t)id * 3;
  o[0] = p[0]; o[1] = p[1]; o[2] = p[2];
  out[OUT_FPS + id] = (float)fi;
}

// one wave per (b,s): first-NS valid indices in ascending n, pad with first valid
__global__ __launch_bounds__(256) void k_ballq(const float* __restrict__ xyz, const int* __restrict__ fps,
                                               int* __restrict__ idxb) {
  int w = (blockIdx.x * 256 + threadIdx.x) >> 6;
  int lane = threadIdx.x & 63;
  int b = w >> 10;
  int fi = fps[w];
  const float* cp = xyz + ((size_t)b * NN + fi) * 3;
  float cx = cp[0], cy = cp[1], cz = cp[2];
  float A = __fadd_rn(__fadd_rn(__fmul_rn(cx, cx), __fmul_rn(cy, cy)), __fmul_rn(cz, cz));
  const float* xb = xyz + (size_t)b * NN * 3;
  int cnt = 0, firstn = -1;
  int* myidx = idxb + (size_t)w * NSMP;
  for (int nb = 0; nb < NN && cnt < NSMP; nb += 64) {
    int n = nb + lane;
    float px = xb[n * 3], py = xb[n * 3 + 1], pz = xb[n * 3 + 2];
    float Bv = __fadd_rn(__fadd_rn(__fmul_rn(px, px), __fmul_rn(py, py)), __fmul_rn(pz, pz));
    float dot = __fadd_rn(__fadd_rn(__fmul_rn(cx, px), __fmul_rn(cy, py)), __fmul_rn(cz, pz));
    float d = __fsub_rn(__fadd_rn(A, Bv), __fmul_rn(2.0f, dot));
    bool valid = !(d > R2);
    unsigned long long mask = __ballot(valid);
    if (firstn < 0 && mask) firstn = nb + __builtin_ctzll(mask);
    int prefix = __popcll(mask & ((1ull << lane) - 1ull));
    int pos = cnt + prefix;
    if (valid && pos < NSMP) myidx[pos] = n;
    cnt += __popcll(mask);
    if (cnt > NSMP) cnt = NSMP;
  }
  if (lane >= cnt) myidx[lane] = firstn;
}

// ---------------- layer 0: gather + GEMM (K=160) -> y0 fp8 + partials ----------------
__global__ __launch_bounds__(256, 2) void k_mlp0(const float* __restrict__ xyz,
                                                 const short* __restrict__ ptsT,
                                                 const int* __restrict__ fps, const int* __restrict__ idxb,
                                                 const short* __restrict__ W0b, const float* __restrict__ b0,
                                                 unsigned char* __restrict__ y0, float* __restrict__ ps,
                                                 float* __restrict__ pq) {
  __shared__ short xs[2][64 * 168];
  __shared__ __align__(16) unsigned char ys8[2][8192];
  __shared__ int smidx[G * 64];
  __shared__ float smc[G][3];
  int t = threadIdx.x;
  int bs0 = blockIdx.x * G;
  int b = bs0 >> 10;  // groups never straddle batches (1024 % 8 == 0)
  // zero both xs buffers (pad cols 131..159 stay 0 forever)
  {
    uint4 z; z.x = 0; z.y = 0; z.z = 0; z.w = 0;
    uint4* xp = (uint4*)&xs[0][0];
    for (int i = t; i < 2 * 64 * 168 * 2 / 16; i += 256) xp[i] = z;
  }
  smidx[t] = idxb[(size_t)bs0 * 64 + t];
  smidx[t + 256] = idxb[(size_t)bs0 * 64 + t + 256];
  if (t < G) {
    int fi = fps[bs0 + t];
    const float* p = xyz + ((size_t)b * NN + fi) * 3;
    smc[t][0] = p[0]; smc[t][1] = p[1]; smc[t][2] = p[2];
  }
  const int lane = t & 63, w = t >> 6, quad = lane >> 4, l15 = lane & 15;
  // weight fragments once per block
  short8 bw[2][5];
#pragma unroll
  for (int j = 0; j < 2; j++)
#pragma unroll
    for (int ks = 0; ks < 5; ks++)
      bw[j][ks] = *(const short8*)&W0b[(w * 32 + j * 16 + l15) * 160 + ks * 32 + quad * 8];
  float bj[2] = {b0[w * 32 + l15], b0[w * 32 + 16 + l15]};
  float rs[2] = {0.f, 0.f}, rq[2] = {0.f, 0.f};
  __syncthreads();  // smidx/smc visible
  const int grow = t >> 2, gpart = t & 3;
  uint4 pf[4], pf2[4];
  float prel[3] = {0, 0, 0}, prel2[3] = {0, 0, 0};
  {
    int n = smidx[grow];
    const uint4* sp = (const uint4*)(ptsT + ((size_t)b * NN + n) * DD);
#pragma unroll
    for (int i = 0; i < 4; i++) pf[i] = sp[gpart * 4 + i];
    if (t < 64) {
      int n2 = smidx[t];
      const float* p = xyz + ((size_t)b * NN + n2) * 3;
      prel[0] = p[0]; prel[1] = p[1]; prel[2] = p[2];
    }
  }
  for (int g = 0; g < G; g++) {
    short* xb = xs[g & 1];
    // stage prefetched gather
#pragma unroll
    for (int i = 0; i < 4; i++) *(uint4*)&xb[grow * 168 + (gpart * 4 + i) * 8] = pf[i];
    if (t < 64) {
      xb[t * 168 + 128] = (short)f2bf(prel[0] - smc[g][0]);
      xb[t * 168 + 129] = (short)f2bf(prel[1] - smc[g][1]);
      xb[t * 168 + 130] = (short)f2bf(prel[2] - smc[g][2]);
    }
    __syncthreads();  // publishes xs[g&1] and ys8[(g-1)&1]
    if (g + 1 < G) {
      int n = smidx[(g + 1) * 64 + grow];
      const uint4* sp = (const uint4*)(ptsT + ((size_t)b * NN + n) * DD);
#pragma unroll
      for (int i = 0; i < 4; i++) pf2[i] = sp[gpart * 4 + i];
      if (t < 64) {
        int n2 = smidx[(g + 1) * 64 + t];
        const float* p = xyz + ((size_t)b * NN + n2) * 3;
        prel2[0] = p[0]; prel2[1] = p[1]; prel2[2] = p[2];
      }
    }
    if (g >= 1) {
      const uint4* yst = (const uint4*)ys8[(g - 1) & 1];
      uint4* dst = (uint4*)(y0 + (size_t)(bs0 + g - 1) * 8192);
      dst[2 * t] = yst[2 * t];
      dst[2 * t + 1] = yst[2 * t + 1];
    }
    float4v acc[2][4];
#pragma unroll
    for (int j = 0; j < 2; j++)
#pragma unroll
      for (int mi = 0; mi < 4; mi++) acc[j][mi] = (float4v){bj[j], bj[j], bj[j], bj[j]};
#pragma unroll
    for (int ks = 0; ks < 5; ks++) {
      short8 am[4];
#pragma unroll
      for (int mi = 0; mi < 4; mi++)
        am[mi] = *(const short8*)&xb[(mi * 16 + l15) * 168 + ks * 32 + quad * 8];
#pragma unroll
      for (int j = 0; j < 2; j++)
#pragma unroll
        for (int mi = 0; mi < 4; mi++)
          acc[j][mi] = __builtin_amdgcn_mfma_f32_16x16x32_bf16(am[mi], bw[j][ks], acc[j][mi], 0, 0, 0);
    }
    unsigned char* yb = ys8[g & 1];
#pragma unroll
    for (int j = 0; j < 2; j++) {
      int col = w * 32 + j * 16 + l15;
#pragma unroll
      for (int mi = 0; mi < 4; mi++)
#pragma unroll
        for (int r = 0; r < 4; r++) {
          float v = acc[j][mi][r];
          rs[j] += v; rq[j] = fmaf(v, v, rq[j]);
          int rowi = mi * 16 + quad * 4 + r;
          int pk = __builtin_amdgcn_cvt_pk_fp8_f32(v, v, 0, false);
          yb[rowi * 128 + col] = (unsigned char)(pk & 0xff);
        }
    }
#pragma unroll
    for (int i = 0; i < 4; i++) pf[i] = pf2[i];
    prel[0] = prel2[0]; prel[1] = prel2[1]; prel[2] = prel2[2];
  }
  __syncthreads();
  {
    const uint4* yst = (const uint4*)ys8[(G - 1) & 1];
    uint4* dst = (uint4*)(y0 + (size_t)(bs0 + G - 1) * 8192);
    dst[2 * t] = yst[2 * t];
    dst[2 * t + 1] = yst[2 * t + 1];
  }
#pragma unroll
  for (int j = 0; j < 2; j++) {
    float s = rs[j], q = rq[j];
    s += __shfl_down(s, 32); q += __shfl_down(q, 32);
    s += __shfl_down(s, 16); q += __shfl_down(q, 16);
    if (lane < 16) {
      int col = w * 32 + j * 16 + l15;
      ps[(size_t)blockIdx.x * 128 + col] = s;
      pq[(size_t)blockIdx.x * 128 + col] = q;
    }
  }
}

// ---------------- layer 1: y0 fp8 -> affine+relu -> GEMM -> y1 fp8 + partials ----------------
__global__ __launch_bounds__(256, 2) void k_mlp1(const unsigned char* __restrict__ y0,
                                                 const float* __restrict__ sc, const float* __restrict__ sh,
                                                 const short* __restrict__ W1b, const float* __restrict__ b1,
                                                 unsigned char* __restrict__ y1, float* __restrict__ ps,
                                                 float* __restrict__ pq) {
  __shared__ short xs[2][64 * 136];
  __shared__ __align__(16) unsigned char ys8[2][8192];
  __shared__ float ssc[128], ssh[128];
  int t = threadIdx.x;
  int bs0 = blockIdx.x * G;
  if (t < 128) { ssc[t] = sc[t]; ssh[t] = sh[t]; }
  const int lane = t & 63, w = t >> 6, quad = lane >> 4, l15 = lane & 15;
  short8 bw[2][4];
#pragma unroll
  for (int j = 0; j < 2; j++)
#pragma unroll
    for (int ks = 0; ks < 4; ks++)
      bw[j][ks] = *(const short8*)&W1b[(w * 32 + j * 16 + l15) * 128 + ks * 32 + quad * 8];
  float bj[2] = {b1[w * 32 + l15], b1[w * 32 + 16 + l15]};
  float rs[2] = {0.f, 0.f}, rq[2] = {0.f, 0.f};
  uint4 pfa, pfb, pfa2, pfb2;
  {
    const uint4* sp = (const uint4*)(y0 + (size_t)bs0 * 8192) + 2 * t;
    pfa = sp[0]; pfb = sp[1];
  }
  pfa2 = pfa; pfb2 = pfb;
  __syncthreads();  // ssc/ssh visible
  const int crow = t >> 2, cb = (t & 3) * 32;
  for (int g = 0; g < G; g++) {
    short* xb = xs[g & 1];
    {
      unsigned dw[8] = {pfa.x, pfa.y, pfa.z, pfa.w, pfb.x, pfb.y, pfb.z, pfb.w};
#pragma unroll
      for (int dd = 0; dd < 8; dd++) {
        int c = cb + dd * 4;
        float f0 = __builtin_amdgcn_cvt_f32_fp8(dw[dd], 0);
        float f1 = __builtin_amdgcn_cvt_f32_fp8(dw[dd], 1);
        float f2 = __builtin_amdgcn_cvt_f32_fp8(dw[dd], 2);
        float f3 = __builtin_amdgcn_cvt_f32_fp8(dw[dd], 3);
        float x0 = fmaxf(fmaf(f0, ssc[c], ssh[c]), 0.f);
        float x1 = fmaxf(fmaf(f1, ssc[c + 1], ssh[c + 1]), 0.f);
        float x2 = fmaxf(fmaf(f2, ssc[c + 2], ssh[c + 2]), 0.f);
        float x3 = fmaxf(fmaf(f3, ssc[c + 3], ssh[c + 3]), 0.f);
        unsigned p0 = (unsigned)f2bf(x0) | ((unsigned)f2bf(x1) << 16);
        unsigned p1 = (unsigned)f2bf(x2) | ((unsigned)f2bf(x3) << 16);
        unsigned* dst = (unsigned*)&xb[crow * 136 + c];
        dst[0] = p0; dst[1] = p1;
      }
    }
    __syncthreads();  // publishes xs[g&1] and ys8[(g-1)&1]
    if (g + 1 < G) {
      const uint4* sp = (const uint4*)(y0 + (size_t)(bs0 + g + 1) * 8192) + 2 * t;
      pfa2 = sp[0]; pfb2 = sp[1];
    }
    if (g >= 1) {
      const uint4* yst = (const uint4*)ys8[(g - 1) & 1];
      uint4* dst = (uint4*)(y1 + (size_t)(bs0 + g - 1) * 8192);
      dst[2 * t] = yst[2 * t];
      dst[2 * t + 1] = yst[2 * t + 1];
    }
    float4v acc[2][4];
#pragma unroll
    for (int j = 0; j < 2; j++)
#pragma unroll
      for (int mi = 0; mi < 4; mi++) acc[j][mi] = (float4v){bj[j], bj[j], bj[j], bj[j]};
#pragma unroll
    for (int ks = 0; ks < 4; ks++) {
      short8 am[4];
#pragma unroll
      for (int mi = 0; mi < 4; mi++)
        am[mi] = *(const short8*)&xb[(mi * 16 + l15) * 136 + ks * 32 + quad * 8];
#pragma unroll
      for (int j = 0; j < 2; j++)
#pragma unroll
        for (int mi = 0; mi < 4; mi++)
          acc[j][mi] = __builtin_amdgcn_mfma_f32_16x16x32_bf16(am[mi], bw[j][ks], acc[j][mi], 0, 0, 0);
    }
    unsigned char* yb = ys8[g & 1];
#pragma unroll
    for (int j = 0; j < 2; j++) {
      int col = w * 32 + j * 16 + l15;
#pragma unroll
      for (int mi = 0; mi < 4; mi++)
#pragma unroll
        for (int r = 0; r < 4; r++) {
          float v = acc[j][mi][r];
          rs[j] += v; rq[j] = fmaf(v, v, rq[j]);
          int rowi = mi * 16 + quad * 4 + r;
          int pk = __builtin_amdgcn_cvt_pk_fp8_f32(v, v, 0, false);
          yb[rowi * 128 + col] = (unsigned char)(pk & 0xff);
        }
    }
    pfa = pfa2; pfb = pfb2;
  }
  __syncthreads();
  {
    const uint4* yst = (const uint4*)ys8[(G - 1) & 1];
    uint4* dst = (uint4*)(y1 + (size_t)(bs0 + G - 1) * 8192);
    dst[2 * t] = yst[2 * t];
    dst[2 * t + 1] = yst[2 * t + 1];
  }
#pragma unroll
  for (int j = 0; j < 2; j++) {
    float s = rs[j], q = rq[j];
    s += __shfl_down(s, 32); q += __shfl_down(q, 32);
    s += __shfl_down(s, 16); q += __shfl_down(q, 16);
    if (lane < 16) {
      int col = w * 32 + j * 16 + l15;
      ps[(size_t)blockIdx.x * 128 + col] = s;
      pq[(size_t)blockIdx.x * 128 + col] = q;
    }
  }
}

// ---------------- layer 2: y1 fp8 -> affine+relu -> GEMM (256 out) -> max/min + partials ----------------
__global__ __launch_bounds__(256, 2) void k_mlp2(const unsigned char* __restrict__ y1,
                                                 const float* __restrict__ sc, const float* __restrict__ sh,
                                                 const short* __restrict__ W2b, const float* __restrict__ b2,
                                                 float* __restrict__ maxb, float* __restrict__ minb,
                                                 float* __restrict__ ps, float* __restrict__ pq) {
  __shared__ short xs[2][64 * 136];
  __shared__ float ssc[128], ssh[128];
  int t = threadIdx.x;
  int bs0 = blockIdx.x * G;
  if (t < 128) { ssc[t] = sc[t]; ssh[t] = sh[t]; }
  const int lane = t & 63, w = t >> 6, quad = lane >> 4, l15 = lane & 15;
  short8 bw[4][4];
#pragma unroll
  for (int j = 0; j < 4; j++)
#pragma unroll
    for (int ks = 0; ks < 4; ks++)
      bw[j][ks] = *(const short8*)&W2b[(w * 64 + j * 16 + l15) * 128 + ks * 32 + quad * 8];
  float bj[4];
#pragma unroll
  for (int j = 0; j < 4; j++) bj[j] = b2[w * 64 + j * 16 + l15];
  float rs[4] = {0.f, 0.f, 0.f, 0.f}, rq[4] = {0.f, 0.f, 0.f, 0.f};
  uint4 pfa, pfb, pfa2, pfb2;
  {
    const uint4* sp = (const uint4*)(y1 + (size_t)bs0 * 8192) + 2 * t;
    pfa = sp[0]; pfb = sp[1];
  }
  pfa2 = pfa; pfb2 = pfb;
  __syncthreads();
  const int crow = t >> 2, cb = (t & 3) * 32;
  for (int g = 0; g < G; g++) {
    short* xb = xs[g & 1];
    {
      unsigned dw[8] = {pfa.x, pfa.y, pfa.z, pfa.w, pfb.x, pfb.y, pfb.z, pfb.w};
#pragma unroll
      for (int dd = 0; dd < 8; dd++) {
        int c = cb + dd * 4;
        float f0 = __builtin_amdgcn_cvt_f32_fp8(dw[dd], 0);
        float f1 = __builtin_amdgcn_cvt_f32_fp8(dw[dd], 1);
        float f2 = __builtin_amdgcn_cvt_f32_fp8(dw[dd], 2);
        float f3 = __builtin_amdgcn_cvt_f32_fp8(dw[dd], 3);
        float x0 = fmaxf(fmaf(f0, ssc[c], ssh[c]), 0.f);
        float x1 = fmaxf(fmaf(f1, ssc[c + 1], ssh[c + 1]), 0.f);
        float x2 = fmaxf(fmaf(f2, ssc[c + 2], ssh[c + 2]), 0.f);
        float x3 = fmaxf(fmaf(f3, ssc[c + 3], ssh[c + 3]), 0.f);
        unsigned p0 = (unsigned)f2bf(x0) | ((unsigned)f2bf(x1) << 16);
        unsigned p1 = (unsigned)f2bf(x2) | ((unsigned)f2bf(x3) << 16);
        unsigned* dst = (unsigned*)&xb[crow * 136 + c];
        dst[0] = p0; dst[1] = p1;
      }
    }
    __syncthreads();
    if (g + 1 < G) {
      const uint4* sp = (const uint4*)(y1 + (size_t)(bs0 + g + 1) * 8192) + 2 * t;
      pfa2 = sp[0]; pfb2 = sp[1];
    }
    float4v acc[4][4];
#pragma unroll
    for (int j = 0; j < 4; j++)
#pragma unroll
      for (int mi = 0; mi < 4; mi++) acc[j][mi] = (float4v){bj[j], bj[j], bj[j], bj[j]};
#pragma unroll
    for (int ks = 0; ks < 4; ks++) {
      short8 am[4];
#pragma unroll
      for (int mi = 0; mi < 4; mi++)
        am[mi] = *(const short8*)&xb[(mi * 16 + l15) * 136 + ks * 32 + quad * 8];
#pragma unroll
      for (int j = 0; j < 4; j++)
#pragma unroll
        for (int mi = 0; mi < 4; mi++)
          acc[j][mi] = __builtin_amdgcn_mfma_f32_16x16x32_bf16(am[mi], bw[j][ks], acc[j][mi], 0, 0, 0);
    }
#pragma unroll
    for (int j = 0; j < 4; j++) {
      float mx = -3.4e38f, mn = 3.4e38f;
#pragma unroll
      for (int mi = 0; mi < 4; mi++)
#pragma unroll
        for (int r = 0; r < 4; r++) {
          float v = acc[j][mi][r];
          rs[j] += v; rq[j] = fmaf(v, v, rq[j]);
          mx = fmaxf(mx, v); mn = fminf(mn, v);
        }
      mx = fmaxf(mx, __shfl_down(mx, 32)); mn = fminf(mn, __shfl_down(mn, 32));
      mx = fmaxf(mx, __shfl_down(mx, 16)); mn = fminf(mn, __shfl_down(mn, 16));
      if (lane < 16) {
        int col = w * 64 + j * 16 + l15;
        maxb[(size_t)(bs0 + g) * 256 + col] = mx;
        minb[(size_t)(bs0 + g) * 256 + col] = mn;
      }
    }
    pfa = pfa2; pfb = pfb2;
  }
#pragma unroll
  for (int j = 0; j < 4; j++) {
    float s = rs[j], q = rq[j];
    s += __shfl_down(s, 32); q += __shfl_down(q, 32);
    s += __shfl_down(s, 16); q += __shfl_down(q, 16);
    if (lane < 16) {
      int col = w * 64 + j * 16 + l15;
      ps[(size_t)blockIdx.x * 256 + col] = s;
      pq[(size_t)blockIdx.x * 256 + col] = q;
    }
  }
}

// parallel partial reduce: grid = nch blocks; P layout [1024][nch]
__global__ __launch_bounds__(256) void k_finp(const float* __restrict__ ps, const float* __restrict__ pq,
                                              const float* __restrict__ g_, const float* __restrict__ be,
                                              float* __restrict__ sc, float* __restrict__ sh, int nch) {
  int ch = blockIdx.x;
  int t = threadIdx.x;
  float s = 0.f, q = 0.f;
#pragma unroll
  for (int b = 0; b < NBLK / 256; b++) {
    int blk = b * 256 + t;
    s += ps[(size_t)blk * nch + ch];
    q += pq[(size_t)blk * nch + ch];
  }
#pragma unroll
  for (int off = 32; off >= 1; off >>= 1) {
    s += __shfl_down(s, off);
    q += __shfl_down(q, off);
  }
  __shared__ float rsm[4], rqm[4];
  if ((t & 63) == 0) { rsm[t >> 6] = s; rqm[t >> 6] = q; }
  __syncthreads();
  if (t == 0) {
    s = rsm[0] + rsm[1] + rsm[2] + rsm[3];
    q = rqm[0] + rqm[1] + rqm[2] + rqm[3];
    const float inv = 1.0f / 524288.0f;
    float m = s * inv;
    float v = fmaf(-m, m, q * inv);
    v = fmaxf(v, 0.f);
    float a = g_[ch] * rsqrtf(v + EPSV);
    sc[ch] = a;
    sh[ch] = fmaf(-m, a, be[ch]);
  }
}

// out[b, o, s] = relu(a*sel + c), sel = max if a>=0 else min
__global__ __launch_bounds__(256) void k_out(const float* __restrict__ maxb, const float* __restrict__ minb,
                                             const float* __restrict__ sc, const float* __restrict__ sh,
                                             float* __restrict__ out) {
  int flat = blockIdx.x * 256 + threadIdx.x;  // 2,097,152
  int b = flat >> 18;
  int o = (flat >> 10) & 255;
  int s = flat & 1023;
  float a = sc[o], c_ = sh[o];
  size_t mi = ((size_t)(b * 1024 + s)) * 256 + o;
  float v = (a >= 0.f) ? maxb[mi] : minb[mi];
  out[OUT_FEAT + flat] = fmaxf(fmaf(a, v, c_), 0.f);
}

extern "C" void kernel_launch(void* const* d_in, const int* in_sizes, int n_in,
                              void* d_out, int out_size, void* d_ws, size_t ws_size,
                              hipStream_t stream) {
  const float* xyz = (const float*)d_in[0];
  const float* pts = (const float*)d_in[1];
  const int* fps = (const int*)d_in[2];
  const float* W0 = (const float*)d_in[3];
  const float* b0 = (const float*)d_in[4];
  const float* g0 = (const float*)d_in[5];
  const float* be0 = (const float*)d_in[6];
  const float* W1 = (const float*)d_in[7];
  const float* b1 = (const float*)d_in[8];
  const float* g1 = (const float*)d_in[9];
  const float* be1 = (const float*)d_in[10];
  const float* W2 = (const float*)d_in[11];
  const float* b2 = (const float*)d_in[12];
  const float* g2 = (const float*)d_in[13];
  const float* be2 = (const float*)d_in[14];
  float* out = (float*)d_out;
  char* ws = (char*)d_ws;

  k_newxyz<<<32, 256, 0, stream>>>(xyz, fps, out);
  if (ws_size < WS_NEEDED) return;

  short* ptsT = (short*)(ws + O_PT);
  unsigned char* y0 = (unsigned char*)(ws + O_Y0);
  unsigned char* y1 = (unsigned char*)(ws + O_Y1);
  int* idxb = (int*)(ws + O_IDX);
  float* maxbf = (float*)(ws + O_MAXB);
  float* minbf = (float*)(ws + O_MINB);
  short* W0b = (short*)(ws + O_W0B);
  short* W1b = (short*)(ws + O_W1B);
  short* W2b = (short*)(ws + O_W2B);
  float* p0s = (float*)(ws + O_P0S);
  float* p0q = (float*)(ws + O_P0Q);
  float* p1s = (float*)(ws + O_P1S);
  float* p1q = (float*)(ws + O_P1Q);
  float* p2s = (float*)(ws + O_P2S);
  float* p2q = (float*)(ws + O_P2Q);
  float* sc0 = (float*)(ws + O_SC0);
  float* sh0 = (float*)(ws + O_SH0);
  float* sc1 = (float*)(ws + O_SC1);
  float* sh1 = (float*)(ws + O_SH1);
  float* sc2 = (float*)(ws + O_SC2);
  float* sh2 = (float*)(ws + O_SH2);

  k_transpose_pts<<<dim3(NN / 32, DD / 32, BB), dim3(32, 8), 0, stream>>>(pts, ptsT);
  k_wt<<<272, 256, 0, stream>>>(W0, W1, W2, W0b, W1b, W2b);
  k_ballq<<<2048, 256, 0, stream>>>(xyz, fps, idxb);
  k_mlp0<<<NBLK, 256, 0, stream>>>(xyz, ptsT, fps, idxb, W0b, b0, y0, p0s, p0q);
  k_finp<<<128, 256, 0, stream>>>(p0s, p0q, g0, be0, sc0, sh0, 128);
  k_mlp1<<<NBLK, 256, 0, stream>>>(y0, sc0, sh0, W1b, b1, y1, p1s, p1q);
  k_finp<<<128, 256, 0, stream>>>(p1s, p1q, g1, be1, sc1, sh1, 128);
  k_mlp2<<<NBLK, 256, 0, stream>>>(y1, sc1, sh1, W2b, b2, maxbf, minbf, p2s, p2q);
  k_finp<<<256, 256, 0, stream>>>(p2s, p2q, g2, be2, sc2, sh2, 256);
  k_out<<<8192, 256, 0, stream>>>(maxbf, minbf, sc2, sh2, out);
}

// Round 4
// 361.889 us; speedup vs baseline: 2.0266x; 1.2027x over previous
//
#include <hip/hip_runtime.h>
#include <hip/hip_bf16.h>

#define BB 8
#define NN 16384
#define SS 1024
#define NSMP 64
#define DD 128
#define R2 0.04f
#define EPSV 1e-5f
#define G 8          // groups (b,s) per mlp block
#define NBLK 1024    // mlp grid

typedef short short8 __attribute__((ext_vector_type(8)));
typedef float float4v __attribute__((ext_vector_type(4)));

static __device__ inline unsigned short f2bf(float f) {
  unsigned u = __builtin_bit_cast(unsigned, f);
  unsigned r = (u + 0x7fffu + ((u >> 16) & 1u)) >> 16;
  return (unsigned short)r;
}

// ---- workspace layout (bytes) ----
#define O_PT    0ull                  // ptsT bf16 [B][N][128]: 33,554,432
#define O_Y0    33554432ull           // y0 fp8: 67,108,864
#define O_Y1    100663296ull          // y1 fp8: 67,108,864
#define O_IDX   167772160ull          // idx int32: 2,097,152
#define O_MAXB  169869312ull          // 8,388,608
#define O_MINB  178257920ull          // 8,388,608
#define O_W0B   186646528ull          // bf16 [128][160]: 40,960
#define O_W1B   186687488ull          // bf16 [128][128]: 32,768
#define O_W2B   186720256ull          // bf16 [256][128]: 65,536
#define O_P0S   186785792ull          // [1024][128] f32: 524,288
#define O_P0Q   187310080ull
#define O_P1S   187834368ull
#define O_P1Q   188358656ull
#define O_P2S   188882944ull          // [1024][256] f32: 1,048,576
#define O_P2Q   189931520ull
#define O_SC0   190980096ull
#define O_SH0   190980608ull
#define O_SC1   190981120ull
#define O_SH1   190981632ull
#define O_SC2   190982144ull          // 1024
#define O_SH2   190983168ull
#define WS_NEEDED 190984192ull

#define OUT_XYZ 0
#define OUT_FEAT 24576
#define OUT_FPS (24576 + 2097152)

// points [B,D,N] fp32 -> ptsT [B,N,D] bf16
__global__ __launch_bounds__(256) void k_transpose_pts(const float* __restrict__ pts,
                                                       short* __restrict__ ptsT) {
  __shared__ float tile[32][33];
  int b = blockIdx.z;
  int n0 = blockIdx.x * 32, c0 = blockIdx.y * 32;
  int tx = threadIdx.x, ty = threadIdx.y;
#pragma unroll
  for (int k = 0; k < 4; k++) {
    int c = c0 + ty + k * 8;
    tile[ty + k * 8][tx] = pts[((size_t)b * DD + c) * NN + n0 + tx];
  }
  __syncthreads();
#pragma unroll
  for (int k = 0; k < 4; k++) {
    int n = n0 + ty + k * 8;
    ptsT[((size_t)b * NN + n) * DD + c0 + tx] = (short)f2bf(tile[tx][ty + k * 8]);
  }
}

// weights -> bf16 rows. W0b[o][kn]: kn 0..127 = feats (orig c=kn+3), 128..130 = xyz, 131..159 = 0.
__global__ __launch_bounds__(256) void k_wt(const float* __restrict__ W0, const float* __restrict__ W1,
                                            const float* __restrict__ W2, short* __restrict__ W0b,
                                            short* __restrict__ W1b, short* __restrict__ W2b) {
  int id = blockIdx.x * 256 + threadIdx.x;
  if (id < 128 * 160) {
    int o = id / 160, kn = id % 160;
    float v = 0.f;
    if (kn < 128) v = W0[o * 131 + kn + 3];
    else if (kn < 131) v = W0[o * 131 + (kn - 128)];
    W0b[id] = (short)f2bf(v);
  } else if (id < 128 * 160 + 128 * 128) {
    int j = id - 128 * 160;
    W1b[j] = (short)f2bf(W1[j]);
  } else if (id < 128 * 160 + 128 * 128 + 256 * 128) {
    int j = id - (128 * 160 + 128 * 128);
    W2b[j] = (short)f2bf(W2[j]);
  }
}

__global__ __launch_bounds__(256) void k_newxyz(const float* __restrict__ xyz, const int* __restrict__ fps,
                                                float* __restrict__ out) {
  int id = blockIdx.x * 256 + threadIdx.x;  // B*S
  int fi = fps[id];
  int b = id >> 10;
  const float* p = xyz + ((size_t)b * NN + fi) * 3;
  float* o = out + OUT_XYZ + (size_t)id * 3;
  o[0] = p[0]; o[1] = p[1]; o[2] = p[2];
  out[OUT_FPS + id] = (float)fi;
}

// one wave per (b,s): first-NS valid indices in ascending n, pad with first valid.
// Unrolled 8x512: all 24 loads issued before the ballot chain -> latency chain /8.
__global__ __launch_bounds__(256) void k_ballq(const float* __restrict__ xyz, const int* __restrict__ fps,
                                               int* __restrict__ idxb) {
  int w = (blockIdx.x * 256 + threadIdx.x) >> 6;
  int lane = threadIdx.x & 63;
  int b = w >> 10;
  int fi = fps[w];
  const float* cp = xyz + ((size_t)b * NN + fi) * 3;
  float cx = cp[0], cy = cp[1], cz = cp[2];
  float A = __fadd_rn(__fadd_rn(__fmul_rn(cx, cx), __fmul_rn(cy, cy)), __fmul_rn(cz, cz));
  const float* xb = xyz + (size_t)b * NN * 3;
  int cnt = 0, firstn = -1;
  int* myidx = idxb + (size_t)w * NSMP;
  for (int nb = 0; nb < NN && cnt < NSMP; nb += 512) {
    float px[8], py[8], pz[8];
#pragma unroll
    for (int u = 0; u < 8; u++) {
      int n = nb + u * 64 + lane;
      px[u] = xb[n * 3]; py[u] = xb[n * 3 + 1]; pz[u] = xb[n * 3 + 2];
    }
#pragma unroll
    for (int u = 0; u < 8; u++) {
      float Bv = __fadd_rn(__fadd_rn(__fmul_rn(px[u], px[u]), __fmul_rn(py[u], py[u])), __fmul_rn(pz[u], pz[u]));
      float dot = __fadd_rn(__fadd_rn(__fmul_rn(cx, px[u]), __fmul_rn(cy, py[u])), __fmul_rn(cz, pz[u]));
      float d = __fsub_rn(__fadd_rn(A, Bv), __fmul_rn(2.0f, dot));
      bool valid = !(d > R2);
      unsigned long long mask = __ballot(valid);
      if (firstn < 0 && mask) firstn = nb + u * 64 + __builtin_ctzll(mask);
      int prefix = __popcll(mask & ((1ull << lane) - 1ull));
      int pos = cnt + prefix;
      if (valid && pos < NSMP) myidx[pos] = nb + u * 64 + lane;
      cnt += __popcll(mask);
      if (cnt > NSMP) cnt = NSMP;
    }
  }
  if (lane >= cnt) myidx[lane] = firstn;
}

// ---------------- layer 0: gather + GEMM (K=160) -> y0 fp8 + partials ----------------
__global__ __launch_bounds__(256, 2) void k_mlp0(const float* __restrict__ xyz,
                                                 const short* __restrict__ ptsT,
                                                 const int* __restrict__ fps, const int* __restrict__ idxb,
                                                 const short* __restrict__ W0b, const float* __restrict__ b0,
                                                 unsigned char* __restrict__ y0, float* __restrict__ ps,
                                                 float* __restrict__ pq) {
  __shared__ short xs[2][64 * 168];
  __shared__ __align__(16) unsigned char ys8[2][8192];
  __shared__ int smidx[G * 64];
  __shared__ float smc[G][3];
  int t = threadIdx.x;
  int bs0 = blockIdx.x * G;
  int b = bs0 >> 10;  // groups never straddle batches (1024 % 8 == 0)
  // zero both xs buffers (pad cols 131..159 stay 0 forever)
  {
    uint4 z; z.x = 0; z.y = 0; z.z = 0; z.w = 0;
    uint4* xp = (uint4*)&xs[0][0];
    for (int i = t; i < 2 * 64 * 168 * 2 / 16; i += 256) xp[i] = z;
  }
  smidx[t] = idxb[(size_t)bs0 * 64 + t];
  smidx[t + 256] = idxb[(size_t)bs0 * 64 + t + 256];
  if (t < G) {
    int fi = fps[bs0 + t];
    const float* p = xyz + ((size_t)b * NN + fi) * 3;
    smc[t][0] = p[0]; smc[t][1] = p[1]; smc[t][2] = p[2];
  }
  const int lane = t & 63, w = t >> 6, quad = lane >> 4, l15 = lane & 15;
  // weight fragments once per block
  short8 bw[2][5];
#pragma unroll
  for (int j = 0; j < 2; j++)
#pragma unroll
    for (int ks = 0; ks < 5; ks++)
      bw[j][ks] = *(const short8*)&W0b[(w * 32 + j * 16 + l15) * 160 + ks * 32 + quad * 8];
  float bj[2] = {b0[w * 32 + l15], b0[w * 32 + 16 + l15]};
  float rs[2] = {0.f, 0.f}, rq[2] = {0.f, 0.f};
  __syncthreads();  // smidx/smc visible
  const int grow = t >> 2, gpart = t & 3;
  uint4 pf[4], pf2[4];
  float prel[3] = {0, 0, 0}, prel2[3] = {0, 0, 0};
  {
    int n = smidx[grow];
    const uint4* sp = (const uint4*)(ptsT + ((size_t)b * NN + n) * DD);
#pragma unroll
    for (int i = 0; i < 4; i++) pf[i] = sp[gpart * 4 + i];
    if (t < 64) {
      int n2 = smidx[t];
      const float* p = xyz + ((size_t)b * NN + n2) * 3;
      prel[0] = p[0]; prel[1] = p[1]; prel[2] = p[2];
    }
  }
  for (int g = 0; g < G; g++) {
    short* xb = xs[g & 1];
    // stage prefetched gather
#pragma unroll
    for (int i = 0; i < 4; i++) *(uint4*)&xb[grow * 168 + (gpart * 4 + i) * 8] = pf[i];
    if (t < 64) {
      xb[t * 168 + 128] = (short)f2bf(prel[0] - smc[g][0]);
      xb[t * 168 + 129] = (short)f2bf(prel[1] - smc[g][1]);
      xb[t * 168 + 130] = (short)f2bf(prel[2] - smc[g][2]);
    }
    __syncthreads();  // publishes xs[g&1] and ys8[(g-1)&1]
    if (g + 1 < G) {
      int n = smidx[(g + 1) * 64 + grow];
      const uint4* sp = (const uint4*)(ptsT + ((size_t)b * NN + n) * DD);
#pragma unroll
      for (int i = 0; i < 4; i++) pf2[i] = sp[gpart * 4 + i];
      if (t < 64) {
        int n2 = smidx[(g + 1) * 64 + t];
        const float* p = xyz + ((size_t)b * NN + n2) * 3;
        prel2[0] = p[0]; prel2[1] = p[1]; prel2[2] = p[2];
      }
    }
    if (g >= 1) {
      const uint4* yst = (const uint4*)ys8[(g - 1) & 1];
      uint4* dst = (uint4*)(y0 + (size_t)(bs0 + g - 1) * 8192);
      dst[2 * t] = yst[2 * t];
      dst[2 * t + 1] = yst[2 * t + 1];
    }
    float4v acc[2][4];
#pragma unroll
    for (int j = 0; j < 2; j++)
#pragma unroll
      for (int mi = 0; mi < 4; mi++) acc[j][mi] = (float4v){bj[j], bj[j], bj[j], bj[j]};
#pragma unroll
    for (int ks = 0; ks < 5; ks++) {
      short8 am[4];
#pragma unroll
      for (int mi = 0; mi < 4; mi++)
        am[mi] = *(const short8*)&xb[(mi * 16 + l15) * 168 + ks * 32 + quad * 8];
#pragma unroll
      for (int j = 0; j < 2; j++)
#pragma unroll
        for (int mi = 0; mi < 4; mi++)
          acc[j][mi] = __builtin_amdgcn_mfma_f32_16x16x32_bf16(am[mi], bw[j][ks], acc[j][mi], 0, 0, 0);
    }
    unsigned char* yb = ys8[g & 1];
#pragma unroll
    for (int j = 0; j < 2; j++) {
      int col = w * 32 + j * 16 + l15;
#pragma unroll
      for (int mi = 0; mi < 4; mi++)
#pragma unroll
        for (int r = 0; r < 4; r++) {
          float v = acc[j][mi][r];
          rs[j] += v; rq[j] = fmaf(v, v, rq[j]);
          int rowi = mi * 16 + quad * 4 + r;
          int pk = __builtin_amdgcn_cvt_pk_fp8_f32(v, v, 0, false);
          yb[rowi * 128 + col] = (unsigned char)(pk & 0xff);
        }
    }
#pragma unroll
    for (int i = 0; i < 4; i++) pf[i] = pf2[i];
    prel[0] = prel2[0]; prel[1] = prel2[1]; prel[2] = prel2[2];
  }
  __syncthreads();
  {
    const uint4* yst = (const uint4*)ys8[(G - 1) & 1];
    uint4* dst = (uint4*)(y0 + (size_t)(bs0 + G - 1) * 8192);
    dst[2 * t] = yst[2 * t];
    dst[2 * t + 1] = yst[2 * t + 1];
  }
#pragma unroll
  for (int j = 0; j < 2; j++) {
    float s = rs[j], q = rq[j];
    s += __shfl_down(s, 32); q += __shfl_down(q, 32);
    s += __shfl_down(s, 16); q += __shfl_down(q, 16);
    if (lane < 16) {
      int col = w * 32 + j * 16 + l15;
      ps[(size_t)blockIdx.x * 128 + col] = s;
      pq[(size_t)blockIdx.x * 128 + col] = q;
    }
  }
}

// ---------------- layer 1: y0 fp8 -> affine+relu -> GEMM -> y1 fp8 + partials ----------------
__global__ __launch_bounds__(256, 2) void k_mlp1(const unsigned char* __restrict__ y0,
                                                 const float* __restrict__ sc, const float* __restrict__ sh,
                                                 const short* __restrict__ W1b, const float* __restrict__ b1,
                                                 unsigned char* __restrict__ y1, float* __restrict__ ps,
                                                 float* __restrict__ pq) {
  __shared__ short xs[2][64 * 136];
  __shared__ __align__(16) unsigned char ys8[2][8192];
  __shared__ float ssc[128], ssh[128];
  int t = threadIdx.x;
  int bs0 = blockIdx.x * G;
  if (t < 128) { ssc[t] = sc[t]; ssh[t] = sh[t]; }
  const int lane = t & 63, w = t >> 6, quad = lane >> 4, l15 = lane & 15;
  short8 bw[2][4];
#pragma unroll
  for (int j = 0; j < 2; j++)
#pragma unroll
    for (int ks = 0; ks < 4; ks++)
      bw[j][ks] = *(const short8*)&W1b[(w * 32 + j * 16 + l15) * 128 + ks * 32 + quad * 8];
  float bj[2] = {b1[w * 32 + l15], b1[w * 32 + 16 + l15]};
  float rs[2] = {0.f, 0.f}, rq[2] = {0.f, 0.f};
  uint4 pfa, pfb, pfa2, pfb2;
  {
    const uint4* sp = (const uint4*)(y0 + (size_t)bs0 * 8192) + 2 * t;
    pfa = sp[0]; pfb = sp[1];
  }
  pfa2 = pfa; pfb2 = pfb;
  __syncthreads();  // ssc/ssh visible
  const int crow = t >> 2, cb = (t & 3) * 32;
  for (int g = 0; g < G; g++) {
    short* xb = xs[g & 1];
    {
      unsigned dw[8] = {pfa.x, pfa.y, pfa.z, pfa.w, pfb.x, pfb.y, pfb.z, pfb.w};
#pragma unroll
      for (int dd = 0; dd < 8; dd++) {
        int c = cb + dd * 4;
        float f0 = __builtin_amdgcn_cvt_f32_fp8(dw[dd], 0);
        float f1 = __builtin_amdgcn_cvt_f32_fp8(dw[dd], 1);
        float f2 = __builtin_amdgcn_cvt_f32_fp8(dw[dd], 2);
        float f3 = __builtin_amdgcn_cvt_f32_fp8(dw[dd], 3);
        float x0 = fmaxf(fmaf(f0, ssc[c], ssh[c]), 0.f);
        float x1 = fmaxf(fmaf(f1, ssc[c + 1], ssh[c + 1]), 0.f);
        float x2 = fmaxf(fmaf(f2, ssc[c + 2], ssh[c + 2]), 0.f);
        float x3 = fmaxf(fmaf(f3, ssc[c + 3], ssh[c + 3]), 0.f);
        unsigned p0 = (unsigned)f2bf(x0) | ((unsigned)f2bf(x1) << 16);
        unsigned p1 = (unsigned)f2bf(x2) | ((unsigned)f2bf(x3) << 16);
        unsigned* dst = (unsigned*)&xb[crow * 136 + c];
        dst[0] = p0; dst[1] = p1;
      }
    }
    __syncthreads();  // publishes xs[g&1] and ys8[(g-1)&1]
    if (g + 1 < G) {
      const uint4* sp = (const uint4*)(y0 + (size_t)(bs0 + g + 1) * 8192) + 2 * t;
      pfa2 = sp[0]; pfb2 = sp[1];
    }
    if (g >= 1) {
      const uint4* yst = (const uint4*)ys8[(g - 1) & 1];
      uint4* dst = (uint4*)(y1 + (size_t)(bs0 + g - 1) * 8192);
      dst[2 * t] = yst[2 * t];
      dst[2 * t + 1] = yst[2 * t + 1];
    }
    float4v acc[2][4];
#pragma unroll
    for (int j = 0; j < 2; j++)
#pragma unroll
      for (int mi = 0; mi < 4; mi++) acc[j][mi] = (float4v){bj[j], bj[j], bj[j], bj[j]};
#pragma unroll
    for (int ks = 0; ks < 4; ks++) {
      short8 am[4];
#pragma unroll
      for (int mi = 0; mi < 4; mi++)
        am[mi] = *(const short8*)&xb[(mi * 16 + l15) * 136 + ks * 32 + quad * 8];
#pragma unroll
      for (int j = 0; j < 2; j++)
#pragma unroll
        for (int mi = 0; mi < 4; mi++)
          acc[j][mi] = __builtin_amdgcn_mfma_f32_16x16x32_bf16(am[mi], bw[j][ks], acc[j][mi], 0, 0, 0);
    }
    unsigned char* yb = ys8[g & 1];
#pragma unroll
    for (int j = 0; j < 2; j++) {
      int col = w * 32 + j * 16 + l15;
#pragma unroll
      for (int mi = 0; mi < 4; mi++)
#pragma unroll
        for (int r = 0; r < 4; r++) {
          float v = acc[j][mi][r];
          rs[j] += v; rq[j] = fmaf(v, v, rq[j]);
          int rowi = mi * 16 + quad * 4 + r;
          int pk = __builtin_amdgcn_cvt_pk_fp8_f32(v, v, 0, false);
          yb[rowi * 128 + col] = (unsigned char)(pk & 0xff);
        }
    }
    pfa = pfa2; pfb = pfb2;
  }
  __syncthreads();
  {
    const uint4* yst = (const uint4*)ys8[(G - 1) & 1];
    uint4* dst = (uint4*)(y1 + (size_t)(bs0 + G - 1) * 8192);
    dst[2 * t] = yst[2 * t];
    dst[2 * t + 1] = yst[2 * t + 1];
  }
#pragma unroll
  for (int j = 0; j < 2; j++) {
    float s = rs[j], q = rq[j];
    s += __shfl_down(s, 32); q += __shfl_down(q, 32);
    s += __shfl_down(s, 16); q += __shfl_down(q, 16);
    if (lane < 16) {
      int col = w * 32 + j * 16 + l15;
      ps[(size_t)blockIdx.x * 128 + col] = s;
      pq[(size_t)blockIdx.x * 128 + col] = q;
    }
  }
}

// ---------------- layer 2: y1 fp8 -> affine+relu -> GEMM (256 out) -> max/min + partials ----------------
__global__ __launch_bounds__(256, 2) void k_mlp2(const unsigned char* __restrict__ y1,
                                                 const float* __restrict__ sc, const float* __restrict__ sh,
                                                 const short* __restrict__ W2b, const float* __restrict__ b2,
                                                 float* __restrict__ maxb, float* __restrict__ minb,
                                                 float* __restrict__ ps, float* __restrict__ pq) {
  __shared__ short xs[2][64 * 136];
  __shared__ float ssc[128], ssh[128];
  int t = threadIdx.x;
  int bs0 = blockIdx.x * G;
  if (t < 128) { ssc[t] = sc[t]; ssh[t] = sh[t]; }
  const int lane = t & 63, w = t >> 6, quad = lane >> 4, l15 = lane & 15;
  short8 bw[4][4];
#pragma unroll
  for (int j = 0; j < 4; j++)
#pragma unroll
    for (int ks = 0; ks < 4; ks++)
      bw[j][ks] = *(const short8*)&W2b[(w * 64 + j * 16 + l15) * 128 + ks * 32 + quad * 8];
  float bj[4];
#pragma unroll
  for (int j = 0; j < 4; j++) bj[j] = b2[w * 64 + j * 16 + l15];
  float rs[4] = {0.f, 0.f, 0.f, 0.f}, rq[4] = {0.f, 0.f, 0.f, 0.f};
  uint4 pfa, pfb, pfa2, pfb2;
  {
    const uint4* sp = (const uint4*)(y1 + (size_t)bs0 * 8192) + 2 * t;
    pfa = sp[0]; pfb = sp[1];
  }
  pfa2 = pfa; pfb2 = pfb;
  __syncthreads();
  const int crow = t >> 2, cb = (t & 3) * 32;
  for (int g = 0; g < G; g++) {
    short* xb = xs[g & 1];
    {
      unsigned dw[8] = {pfa.x, pfa.y, pfa.z, pfa.w, pfb.x, pfb.y, pfb.z, pfb.w};
#pragma unroll
      for (int dd = 0; dd < 8; dd++) {
        int c = cb + dd * 4;
        float f0 = __builtin_amdgcn_cvt_f32_fp8(dw[dd], 0);
        float f1 = __builtin_amdgcn_cvt_f32_fp8(dw[dd], 1);
        float f2 = __builtin_amdgcn_cvt_f32_fp8(dw[dd], 2);
        float f3 = __builtin_amdgcn_cvt_f32_fp8(dw[dd], 3);
        float x0 = fmaxf(fmaf(f0, ssc[c], ssh[c]), 0.f);
        float x1 = fmaxf(fmaf(f1, ssc[c + 1], ssh[c + 1]), 0.f);
        float x2 = fmaxf(fmaf(f2, ssc[c + 2], ssh[c + 2]), 0.f);
        float x3 = fmaxf(fmaf(f3, ssc[c + 3], ssh[c + 3]), 0.f);
        unsigned p0 = (unsigned)f2bf(x0) | ((unsigned)f2bf(x1) << 16);
        unsigned p1 = (unsigned)f2bf(x2) | ((unsigned)f2bf(x3) << 16);
        unsigned* dst = (unsigned*)&xb[crow * 136 + c];
        dst[0] = p0; dst[1] = p1;
      }
    }
    __syncthreads();
    if (g + 1 < G) {
      const uint4* sp = (const uint4*)(y1 + (size_t)(bs0 + g + 1) * 8192) + 2 * t;
      pfa2 = sp[0]; pfb2 = sp[1];
    }
    float4v acc[4][4];
#pragma unroll
    for (int j = 0; j < 4; j++)
#pragma unroll
      for (int mi = 0; mi < 4; mi++) acc[j][mi] = (float4v){bj[j], bj[j], bj[j], bj[j]};
#pragma unroll
    for (int ks = 0; ks < 4; ks++) {
      short8 am[4];
#pragma unroll
      for (int mi = 0; mi < 4; mi++)
        am[mi] = *(const short8*)&xb[(mi * 16 + l15) * 136 + ks * 32 + quad * 8];
#pragma unroll
      for (int j = 0; j < 4; j++)
#pragma unroll
        for (int mi = 0; mi < 4; mi++)
          acc[j][mi] = __builtin_amdgcn_mfma_f32_16x16x32_bf16(am[mi], bw[j][ks], acc[j][mi], 0, 0, 0);
    }
#pragma unroll
    for (int j = 0; j < 4; j++) {
      float mx = -3.4e38f, mn = 3.4e38f;
#pragma unroll
      for (int mi = 0; mi < 4; mi++)
#pragma unroll
        for (int r = 0; r < 4; r++) {
          float v = acc[j][mi][r];
          rs[j] += v; rq[j] = fmaf(v, v, rq[j]);
          mx = fmaxf(mx, v); mn = fminf(mn, v);
        }
      mx = fmaxf(mx, __shfl_down(mx, 32)); mn = fminf(mn, __shfl_down(mn, 32));
      mx = fmaxf(mx, __shfl_down(mx, 16)); mn = fminf(mn, __shfl_down(mn, 16));
      if (lane < 16) {
        int col = w * 64 + j * 16 + l15;
        maxb[(size_t)(bs0 + g) * 256 + col] = mx;
        minb[(size_t)(bs0 + g) * 256 + col] = mn;
      }
    }
    pfa = pfa2; pfb = pfb2;
  }
#pragma unroll
  for (int j = 0; j < 4; j++) {
    float s = rs[j], q = rq[j];
    s += __shfl_down(s, 32); q += __shfl_down(q, 32);
    s += __shfl_down(s, 16); q += __shfl_down(q, 16);
    if (lane < 16) {
      int col = w * 64 + j * 16 + l15;
      ps[(size_t)blockIdx.x * 256 + col] = s;
      pq[(size_t)blockIdx.x * 256 + col] = q;
    }
  }
}

// parallel partial reduce: grid = nch blocks; P layout [1024][nch]
__global__ __launch_bounds__(256) void k_finp(const float* __restrict__ ps, const float* __restrict__ pq,
                                              const float* __restrict__ g_, const float* __restrict__ be,
                                              float* __restrict__ sc, float* __restrict__ sh, int nch) {
  int ch = blockIdx.x;
  int t = threadIdx.x;
  float s = 0.f, q = 0.f;
#pragma unroll
  for (int b = 0; b < NBLK / 256; b++) {
    int blk = b * 256 + t;
    s += ps[(size_t)blk * nch + ch];
    q += pq[(size_t)blk * nch + ch];
  }
#pragma unroll
  for (int off = 32; off >= 1; off >>= 1) {
    s += __shfl_down(s, off);
    q += __shfl_down(q, off);
  }
  __shared__ float rsm[4], rqm[4];
  if ((t & 63) == 0) { rsm[t >> 6] = s; rqm[t >> 6] = q; }
  __syncthreads();
  if (t == 0) {
    s = rsm[0] + rsm[1] + rsm[2] + rsm[3];
    q = rqm[0] + rqm[1] + rqm[2] + rqm[3];
    const float inv = 1.0f / 524288.0f;
    float m = s * inv;
    float v = fmaf(-m, m, q * inv);
    v = fmaxf(v, 0.f);
    float a = g_[ch] * rsqrtf(v + EPSV);
    sc[ch] = a;
    sh[ch] = fmaf(-m, a, be[ch]);
  }
}

// out[b, o, s] = relu(a*sel + c); tiled LDS transpose: coalesced reads (o fast),
// 256B-segment writes (s fast). Block = (b, 32-s tile).
__global__ __launch_bounds__(256) void k_out(const float* __restrict__ maxb, const float* __restrict__ minb,
                                             const float* __restrict__ sc, const float* __restrict__ sh,
                                             float* __restrict__ out) {
  __shared__ float tile[32][257];
  int t = threadIdx.x;
  int blk = blockIdx.x;            // 256 = 8 b x 32 s-tiles
  int b = blk >> 5;
  int s0 = (blk & 31) * 32;
  float a = sc[t], c_ = sh[t];
  bool useMax = (a >= 0.f);
#pragma unroll 4
  for (int r = 0; r < 32; r++) {
    size_t mi = ((size_t)(b * 1024 + s0 + r)) * 256 + t;
    float v = useMax ? maxb[mi] : minb[mi];
    tile[r][t] = fmaxf(fmaf(a, v, c_), 0.f);
  }
  __syncthreads();
  int so = t & 31, oo = t >> 5;    // 8 o-rows x 32 s per iteration
#pragma unroll 8
  for (int ob = 0; ob < 256; ob += 8) {
    int o = ob + oo;
    out[OUT_FEAT + ((size_t)(b * 256 + o) << 10) + s0 + so] = tile[so][o];
  }
}

extern "C" void kernel_launch(void* const* d_in, const int* in_sizes, int n_in,
                              void* d_out, int out_size, void* d_ws, size_t ws_size,
                              hipStream_t stream) {
  const float* xyz = (const float*)d_in[0];
  const float* pts = (const float*)d_in[1];
  const int* fps = (const int*)d_in[2];
  const float* W0 = (const float*)d_in[3];
  const float* b0 = (const float*)d_in[4];
  const float* g0 = (const float*)d_in[5];
  const float* be0 = (const float*)d_in[6];
  const float* W1 = (const float*)d_in[7];
  const float* b1 = (const float*)d_in[8];
  const float* g1 = (const float*)d_in[9];
  const float* be1 = (const float*)d_in[10];
  const float* W2 = (const float*)d_in[11];
  const float* b2 = (const float*)d_in[12];
  const float* g2 = (const float*)d_in[13];
  const float* be2 = (const float*)d_in[14];
  float* out = (float*)d_out;
  char* ws = (char*)d_ws;

  k_newxyz<<<32, 256, 0, stream>>>(xyz, fps, out);
  if (ws_size < WS_NEEDED) return;

  short* ptsT = (short*)(ws + O_PT);
  unsigned char* y0 = (unsigned char*)(ws + O_Y0);
  unsigned char* y1 = (unsigned char*)(ws + O_Y1);
  int* idxb = (int*)(ws + O_IDX);
  float* maxbf = (float*)(ws + O_MAXB);
  float* minbf = (float*)(ws + O_MINB);
  short* W0b = (short*)(ws + O_W0B);
  short* W1b = (short*)(ws + O_W1B);
  short* W2b = (short*)(ws + O_W2B);
  float* p0s = (float*)(ws + O_P0S);
  float* p0q = (float*)(ws + O_P0Q);
  float* p1s = (float*)(ws + O_P1S);
  float* p1q = (float*)(ws + O_P1Q);
  float* p2s = (float*)(ws + O_P2S);
  float* p2q = (float*)(ws + O_P2Q);
  float* sc0 = (float*)(ws + O_SC0);
  float* sh0 = (float*)(ws + O_SH0);
  float* sc1 = (float*)(ws + O_SC1);
  float* sh1 = (float*)(ws + O_SH1);
  float* sc2 = (float*)(ws + O_SC2);
  float* sh2 = (float*)(ws + O_SH2);

  k_transpose_pts<<<dim3(NN / 32, DD / 32, BB), dim3(32, 8), 0, stream>>>(pts, ptsT);
  k_wt<<<272, 256, 0, stream>>>(W0, W1, W2, W0b, W1b, W2b);
  k_ballq<<<2048, 256, 0, stream>>>(xyz, fps, idxb);
  k_mlp0<<<NBLK, 256, 0, stream>>>(xyz, ptsT, fps, idxb, W0b, b0, y0, p0s, p0q);
  k_finp<<<128, 256, 0, stream>>>(p0s, p0q, g0, be0, sc0, sh0, 128);
  k_mlp1<<<NBLK, 256, 0, stream>>>(y0, sc0, sh0, W1b, b1, y1, p1s, p1q);
  k_finp<<<128, 256, 0, stream>>>(p1s, p1q, g1, be1, sc1, sh1, 128);
  k_mlp2<<<NBLK, 256, 0, stream>>>(y1, sc1, sh1, W2b, b2, maxbf, minbf, p2s, p2q);
  k_finp<<<256, 256, 0, stream>>>(p2s, p2q, g2, be2, sc2, sh2, 256);
  k_out<<<256, 256, 0, stream>>>(maxbf, minbf, sc2, sh2, out);
}